// Round 9
// baseline (514.178 us; speedup 1.0000x reference)
//
#include <hip/hip_runtime.h>
#include <hip/hip_bf16.h>
#include <stdint.h>

#define LSEQ 200
#define DDIM 128

typedef __attribute__((ext_vector_type(8))) __bf16 bf16x8;
typedef __attribute__((ext_vector_type(4))) float f32x4;

__device__ __forceinline__ float fast_exp(float x) {
  return __builtin_amdgcn_exp2f(x * 1.4426950408889634f);
}
__device__ __forceinline__ float fast_sigmoid(float x) {
  return __builtin_amdgcn_rcpf(1.0f + fast_exp(-x));
}
__device__ __forceinline__ float fast_tanh(float x) {
  float ax = __builtin_fabsf(x);
  float t = __builtin_amdgcn_exp2f(ax * -2.885390081777927f);  // exp(-2|x|)
  float r = (1.0f - t) * __builtin_amdgcn_rcpf(1.0f + t);
  return x < 0.0f ? -r : r;
}
__device__ __forceinline__ f32x4 mfma16(bf16x8 a, bf16x8 b, f32x4 c) {
  return __builtin_amdgcn_mfma_f32_16x16x32_bf16(a, b, c, 0, 0, 0);
}

// Kernel 1 (unchanged): scores + masked softmax -> attnT (block-major,
// 0 where masked), and h_states fp32 -> bf16 xp packed in frag order:
// xp[((b16*L + t)*4 + kt)*64 + lane] elem j = x[b16*16+(lane&15)][t][kt*32+(lane>>4)*8+j]
__global__ __launch_bounds__(512) void k_scores(
    const float* __restrict__ h_states, const float* __restrict__ target,
    const int* __restrict__ mask, uint4* __restrict__ xp,
    float* __restrict__ attnT, int B) {
  __shared__ float s_sc[4][16][LSEQ];
  __shared__ float s_tgt[16][DDIM];
  const int b16 = blockIdx.x;
  const int bb = b16 * 16;
  const int tid = threadIdx.x;
  for (int i = tid; i < 16 * DDIM; i += 512)
    s_tgt[i >> 7][i & 127] = target[(size_t)(bb + (i >> 7)) * DDIM + (i & 127)];
  __syncthreads();

  {
    const int lane = tid & 63;
    const int kt = (tid >> 6) & 3;
    const int tp = tid >> 8;
    const int row = lane & 15;
    const int hi = lane >> 4;
    const int kbase = kt * 32 + hi * 8;
    const float* src = h_states + ((size_t)(bb + row) * LSEQ) * DDIM + kbase;
    const float* tg = &s_tgt[row][kbase];
#pragma unroll 2
    for (int t = tp; t < LSEQ; t += 2) {
      float4 a = *(const float4*)(src + (size_t)t * DDIM);
      float4 b = *(const float4*)(src + (size_t)t * DDIM + 4);
      float dv = (a.x * tg[0] + a.y * tg[1] + a.z * tg[2] + a.w * tg[3]) +
                 (b.x * tg[4] + b.y * tg[5] + b.z * tg[6] + b.w * tg[7]);
      dv += __shfl_xor(dv, 16);
      dv += __shfl_xor(dv, 32);
      if (hi == 0) s_sc[kt][row][t] = dv;
      union { __bf16 h[8]; uint4 v; } pk;
      pk.h[0] = (__bf16)a.x; pk.h[1] = (__bf16)a.y; pk.h[2] = (__bf16)a.z; pk.h[3] = (__bf16)a.w;
      pk.h[4] = (__bf16)b.x; pk.h[5] = (__bf16)b.y; pk.h[6] = (__bf16)b.z; pk.h[7] = (__bf16)b.w;
      xp[(((size_t)b16 * LSEQ + t) * 4 + kt) * 64 + lane] = pk.v;
    }
  }
  __syncthreads();

  if (tid < 256) {
    const int r2 = tid >> 4;
    const int j = tid & 15;
    const int* mrow = mask + (size_t)(bb + r2) * LSEQ;
    float mx = -3.0e38f;
    for (int t = j; t < LSEQ; t += 16) {
      float s = (s_sc[0][r2][t] + s_sc[1][r2][t]) + (s_sc[2][r2][t] + s_sc[3][r2][t]);
      s *= 0.088388347648318447f;  // 1/sqrt(128)
      s = (mrow[t] != 0) ? s : -3.0e38f;
      s_sc[0][r2][t] = s;
      mx = fmaxf(mx, s);
    }
    mx = fmaxf(mx, __shfl_xor(mx, 1));
    mx = fmaxf(mx, __shfl_xor(mx, 2));
    mx = fmaxf(mx, __shfl_xor(mx, 4));
    mx = fmaxf(mx, __shfl_xor(mx, 8));
    float se = 0.0f;
    for (int t = j; t < LSEQ; t += 16) {
      float e = fast_exp(s_sc[0][r2][t] - mx);
      s_sc[1][r2][t] = e;
      se += e;
    }
    se += __shfl_xor(se, 1);
    se += __shfl_xor(se, 2);
    se += __shfl_xor(se, 4);
    se += __shfl_xor(se, 8);
    float rs = __builtin_amdgcn_rcpf(se);
    for (int t = j; t < LSEQ; t += 16)
      attnT[((size_t)b16 * LSEQ + t) * 16 + r2] =
          (mrow[t] != 0) ? s_sc[1][r2][t] * rs : 0.0f;
  }
}

#define LGKM_BARRIER()                                 \
  asm volatile("s_waitcnt lgkmcnt(0)" ::: "memory");   \
  __builtin_amdgcn_s_barrier();                        \
  asm volatile("" ::: "memory")

// One step for TWO independent batch groups. Operand-swapped MFMAs
// (A = weight frags, B = h/x frags). Group 1's chains fill group 0's
// LDS latency and vice versa. The x(t+2) prefetch is issued in phase B
// AFTER the last consumption of XC (x-part h-tilde MFMAs), so in-place
// reload of the same buffer is sequenced correctly.
#define STEP(t, XC0, XC1)                                                    \
  do {                                                                       \
    float att0 = s_att[(t)][rA];                                             \
    float att1 = s_att[(t)][16 + rA];                                        \
    bf16x8 hf0[4], hf1[4];                                                   \
    _Pragma("unroll") for (int kt = 0; kt < 4; ++kt) {                       \
      hf0[kt] = __builtin_bit_cast(bf16x8, s_hb_f[0][kt][lane]);             \
      hf1[kt] = __builtin_bit_cast(bf16x8, s_hb_f[1][kt][lane]);             \
    }                                                                        \
    f32x4 r0a = vbr, u0a = vbu, r1a = vbr, u1a = vbu;                        \
    _Pragma("unroll") for (int kt = 0; kt < 4; ++kt) { /* x-part, no LDS */  \
      bf16x8 b0 = __builtin_bit_cast(bf16x8, XC0[kt]);                       \
      bf16x8 b1 = __builtin_bit_cast(bf16x8, XC1[kt]);                       \
      r0a = mfma16(wr[kt], b0, r0a);                                         \
      u0a = mfma16(wu[kt], b0, u0a);                                         \
      r1a = mfma16(wr[kt], b1, r1a);                                         \
      u1a = mfma16(wu[kt], b1, u1a);                                         \
    }                                                                        \
    f32x4 r0b = {0.f,0.f,0.f,0.f}, u0b = {0.f,0.f,0.f,0.f};                  \
    f32x4 r1b = {0.f,0.f,0.f,0.f}, u1b = {0.f,0.f,0.f,0.f};                  \
    _Pragma("unroll") for (int kt = 0; kt < 4; ++kt) { /* h-part */          \
      r0b = mfma16(wr[4 + kt], hf0[kt], r0b);                                \
      u0b = mfma16(wu[4 + kt], hf0[kt], u0b);                                \
      r1b = mfma16(wr[4 + kt], hf1[kt], r1b);                                \
      u1b = mfma16(wu[4 + kt], hf1[kt], u1b);                                \
    }                                                                        \
    f32x4 accr0 = r0a + r0b, accu0 = u0a + u0b;                              \
    f32x4 accr1 = r1a + r1b, accu1 = u1a + u1b;                              \
    float uu0[4], uu1[4];                                                    \
    union { __bf16 h[4]; uint2 v; } rhv0, rhv1;                              \
    _Pragma("unroll") for (int j = 0; j < 4; ++j) {                          \
      rhv0.h[j] = (__bf16)(fast_sigmoid(accr0[j]) * hD0[j]);                 \
      rhv1.h[j] = (__bf16)(fast_sigmoid(accr1[j]) * hD1[j]);                 \
      uu0[j] = fast_sigmoid(accu0[j]);                                       \
      uu1[j] = fast_sigmoid(accu1[j]);                                       \
    }                                                                        \
    *rh_w0 = rhv0.v;                                                         \
    *rh_w1 = rhv1.v;                                                         \
    LGKM_BARRIER();                                                          \
    bf16x8 rf0[4], rf1[4];                                                   \
    _Pragma("unroll") for (int kt = 0; kt < 4; ++kt) {                       \
      rf0[kt] = __builtin_bit_cast(bf16x8, s_rh_f[0][kt][lane]);             \
      rf1[kt] = __builtin_bit_cast(bf16x8, s_rh_f[1][kt][lane]);             \
    }                                                                        \
    f32x4 h0a = vbh, h1a = vbh;                                              \
    _Pragma("unroll") for (int kt = 0; kt < 4; ++kt) { /* last use of XC */  \
      h0a = mfma16(wh[kt], __builtin_bit_cast(bf16x8, XC0[kt]), h0a);        \
      h1a = mfma16(wh[kt], __builtin_bit_cast(bf16x8, XC1[kt]), h1a);        \
    }                                                                        \
    { /* in-place prefetch of x(t+2): sequenced AFTER all XC reads */        \
      const int tl = ((t) + 2 < LSEQ) ? (t) + 2 : LSEQ - 1;                  \
      _Pragma("unroll") for (int kt = 0; kt < 4; ++kt) {                     \
        XC0[kt] = xpb0[(size_t)tl * 256 + kt * 64];                          \
        XC1[kt] = xpb1[(size_t)tl * 256 + kt * 64];                          \
      }                                                                      \
    }                                                                        \
    f32x4 h0b = {0.f,0.f,0.f,0.f}, h1b = {0.f,0.f,0.f,0.f};                  \
    _Pragma("unroll") for (int kt = 0; kt < 4; ++kt) { /* h-part */          \
      h0b = mfma16(wh[4 + kt], rf0[kt], h0b);                                \
      h1b = mfma16(wh[4 + kt], rf1[kt], h1b);                                \
    }                                                                        \
    f32x4 acch0 = h0a + h0b, acch1 = h1a + h1b;                              \
    union { __bf16 h[4]; uint2 v; } hbv0, hbv1;                              \
    _Pragma("unroll") for (int j = 0; j < 4; ++j) {                          \
      float up0 = att0 * uu0[j];                                             \
      hD0[j] += up0 * (fast_tanh(acch0[j]) - hD0[j]);                        \
      hbv0.h[j] = (__bf16)hD0[j];                                            \
      float up1 = att1 * uu1[j];                                             \
      hD1[j] += up1 * (fast_tanh(acch1[j]) - hD1[j]);                        \
      hbv1.h[j] = (__bf16)hD1[j];                                            \
    }                                                                        \
    *hb_w0 = hbv0.v;                                                         \
    *hb_w1 = hbv1.v;                                                         \
    LGKM_BARRIER();                                                          \
  } while (0)

__global__ __launch_bounds__(512, 2) void k_recur(
    const uint4* __restrict__ xp, const float* __restrict__ attnT,
    const float* __restrict__ Wr, const float* __restrict__ br,
    const float* __restrict__ Wu, const float* __restrict__ bu,
    const float* __restrict__ Wh, const float* __restrict__ bh,
    float* __restrict__ out, int B) {
  // Per group g: h and r*h staged in LDS in B-frag layout:
  // cell [g][kt][l] elem j = value[batch = l&15][d = kt*32 + (l>>4)*8 + j].
  __shared__ uint4 s_hb_f[2][4][64];
  __shared__ uint4 s_rh_f[2][4][64];
  __shared__ float s_att[LSEQ][32];
  const int tid = threadIdx.x;
  const int lane = tid & 63;
  const int wv = tid >> 6;
  const int b32 = blockIdx.x;
  const int bb = b32 * 32;
  const int q = lane >> 4;
  const int rA = lane & 15;
  const int col = wv * 16 + rA;  // weight-loading column

  // Weights -> bf16 frags in VGPRs (A-operand; shared by both groups)
  bf16x8 wr[8], wu[8], wh[8];
#pragma unroll
  for (int kt = 0; kt < 8; ++kt) {
    bf16x8 tr, tu, th;
    int krow = kt * 32 + q * 8;
#pragma unroll
    for (int j = 0; j < 8; ++j) {
      tr[j] = (__bf16)Wr[(size_t)(krow + j) * DDIM + col];
      tu[j] = (__bf16)Wu[(size_t)(krow + j) * DDIM + col];
      th[j] = (__bf16)Wh[(size_t)(krow + j) * DDIM + col];
    }
    wr[kt] = tr; wu[kt] = tu; wh[kt] = th;
  }
  const int cbase = wv * 16 + q * 4;
  f32x4 vbr = {br[cbase], br[cbase + 1], br[cbase + 2], br[cbase + 3]};
  f32x4 vbu = {bu[cbase], bu[cbase + 1], bu[cbase + 2], bu[cbase + 3]};
  f32x4 vbh = {bh[cbase], bh[cbase + 1], bh[cbase + 2], bh[cbase + 3]};

  // attn for both groups: s_att[t][g*16 + r]
  for (int i = tid; i < LSEQ * 32; i += 512) {
    int t = i >> 5, gr = (i >> 4) & 1, r = i & 15;
    s_att[t][gr * 16 + r] =
        attnT[((size_t)(b32 * 2 + gr) * LSEQ + t) * 16 + r];
  }
  ((uint4*)s_hb_f)[tid] = (uint4){0, 0, 0, 0};  // zero [2][4][64] = 512 cells

  // Writer: thread's 4 values (batch rA, cols cbase..+3) -> one b64 at
  // frag [wv>>1][rA + 16*((wv&1)*2 + (q>>1))], elems (q&1)*4..+3.
  const int w_off = (wv >> 1) * 1024 + (rA + 16 * ((wv & 1) * 2 + (q >> 1))) * 16 + (q & 1) * 8;
  uint2* hb_w0 = (uint2*)((char*)&s_hb_f[0][0][0] + w_off);
  uint2* hb_w1 = (uint2*)((char*)&s_hb_f[1][0][0] + w_off);
  uint2* rh_w0 = (uint2*)((char*)&s_rh_f[0][0][0] + w_off);
  uint2* rh_w1 = (uint2*)((char*)&s_rh_f[1][0][0] + w_off);

  const uint4* xpb0 = xp + (size_t)(b32 * 2) * LSEQ * 256 + lane;
  const uint4* xpb1 = xp + (size_t)(b32 * 2 + 1) * LSEQ * 256 + lane;

  // Double-buffered x frags per group: A = x(0), B = x(1).
  // STEP(t) consumes A then reloads A <- x(t+2) after last use (in-macro).
  uint4 xA0[4], xB0[4], xA1[4], xB1[4];
#pragma unroll
  for (int kt = 0; kt < 4; ++kt) {
    xA0[kt] = xpb0[kt * 64];
    xA1[kt] = xpb1[kt * 64];
    xB0[kt] = xpb0[256 + kt * 64];
    xB1[kt] = xpb1[256 + kt * 64];
  }
  float hD0[4] = {0.f, 0.f, 0.f, 0.f};
  float hD1[4] = {0.f, 0.f, 0.f, 0.f};
  __syncthreads();

  for (int t = 0; t < LSEQ; t += 2) {
    STEP(t, xA0, xA1);      // consume x(t) from A, reload A <- x(t+2)
    STEP(t + 1, xB0, xB1);  // consume x(t+1) from B, reload B <- x(t+3)
  }

  float4 o0 = {hD0[0], hD0[1], hD0[2], hD0[3]};
  *(float4*)(out + (size_t)(bb + rA) * DDIM + cbase) = o0;
  float4 o1 = {hD1[0], hD1[1], hD1[2], hD1[3]};
  *(float4*)(out + (size_t)(bb + 16 + rA) * DDIM + cbase) = o1;
}

extern "C" void kernel_launch(void* const* d_in, const int* in_sizes, int n_in,
                              void* d_out, int out_size, void* d_ws, size_t ws_size,
                              hipStream_t stream) {
  const float* h_states = (const float*)d_in[0];
  const float* target   = (const float*)d_in[1];
  const int*   mask     = (const int*)d_in[2];
  const float* Wr = (const float*)d_in[3];
  const float* br = (const float*)d_in[4];
  const float* Wu = (const float*)d_in[5];
  const float* bu = (const float*)d_in[6];
  const float* Wh = (const float*)d_in[7];
  const float* bh = (const float*)d_in[8];

  const int B = in_sizes[0] / (LSEQ * DDIM);  // 4096
  uint4* xp = (uint4*)d_ws;                    // B*L*128 bf16 frags
  float* attnT = (float*)((char*)d_ws + (size_t)B * LSEQ * DDIM * 2);

  k_scores<<<B / 16, 512, 0, stream>>>(h_states, target, mask, xp, attnT, B);
  k_recur<<<B / 32, 512, 0, stream>>>(xp, attnT, Wr, br, Wu, bu, Wh, bh,
                                      (float*)d_out, B);
}